// Round 4
// baseline (102.253 us; speedup 1.0000x reference)
//
#include <hip/hip_runtime.h>
#include <math.h>

// TripletHard B=8192 D=128 NC=256. MFMA bf16 Gram + streaming min-tracking.
// v[i][j] = sq_j - 2*dot(i,j) tracked (monotone shift by sq_i applied at end).
// fbT is K-MAJOR chunked: fbT8[kc * 8192 + row] holds features[row][kc*8..kc*8+7]
// (kc = 0..15). This makes LDS tiles contiguous per (kc, row-range) so
// global_load_lds width-16 can stage them (wave-uniform dest + lane*16), and
// gives 16B lane stride on ds_read_b128 (2-way alias = free).
// ws: [0,32K) sq fp32[8192]; [32K,32K+2M) fbT; [32K+2M,+1M) part float4[8][8192];
//     then g_acc float, counter uint.

#define BN 8192
#define MARGIN_F 1.0f
#define EPS_F 1e-5f

typedef __attribute__((ext_vector_type(8))) short short8;
typedef __attribute__((ext_vector_type(4))) float floatx4;

__device__ __forceinline__ unsigned short bf16_rne(float x, float& r) {
    unsigned u = __float_as_uint(x);
    u += 0x7FFF + ((u >> 16) & 1);
    unsigned short h = (unsigned short)(u >> 16);
    r = __uint_as_float(((unsigned)h) << 16);
    return h;
}

// 4 threads per row: convert to bf16 (RNE), write K-major chunks, sq from
// ROUNDED values. Also zero-inits the merge kernel's acc/counter.
__global__ __launch_bounds__(256) void prep_kernel(const float* __restrict__ f,
                                                   short8* __restrict__ fbT,
                                                   float* __restrict__ sq,
                                                   float* __restrict__ g_acc,
                                                   unsigned* __restrict__ counter) {
    int gid = blockIdx.x * 256 + threadIdx.x;  // 0..32767
    if (gid == 0) { *g_acc = 0.f; *counter = 0u; }
    int row = gid >> 2, part = gid & 3;
    const float4* f4 = (const float4*)f + (size_t)row * 32 + part * 8;
    float s = 0.f;
#pragma unroll
    for (int cc = 0; cc < 4; ++cc) {  // chunk kc = part*4 + cc
        float4 v0 = f4[cc * 2], v1 = f4[cc * 2 + 1];
        float r0, r1, r2, r3, r4, r5, r6, r7;
        short8 o;
        o[0] = (short)bf16_rne(v0.x, r0);
        o[1] = (short)bf16_rne(v0.y, r1);
        o[2] = (short)bf16_rne(v0.z, r2);
        o[3] = (short)bf16_rne(v0.w, r3);
        o[4] = (short)bf16_rne(v1.x, r4);
        o[5] = (short)bf16_rne(v1.y, r5);
        o[6] = (short)bf16_rne(v1.z, r6);
        o[7] = (short)bf16_rne(v1.w, r7);
        fbT[(size_t)(part * 4 + cc) * BN + row] = o;
        s += r0 * r0 + r1 * r1 + r2 * r2 + r3 * r3 +
             r4 * r4 + r5 * r5 + r6 * r6 + r7 * r7;
    }
    s += __shfl_xor(s, 1, 4);
    s += __shfl_xor(s, 2, 4);
    if (part == 0) sq[row] = s;
}

// Issue one wave's share of a 128-row B-tile stage: 8 x global_load_lds(16B).
// Dest chunk index = wv*512 + it*64 + lane (contiguous per instr); kc = idx>>7,
// r = idx&127 -> source fbT8[kc*8192 + j0 + r] is contiguous per instr too.
__device__ __forceinline__ void stage_tile(const short8* __restrict__ fbT,
                                           short8* buf, int j0, int wv, int lane) {
#pragma unroll
    for (int it = 0; it < 8; ++it) {
        int cb = wv * 512 + it * 64;  // wave-uniform
        int kc = cb >> 7, r0 = cb & 127;
        const short8* g = fbT + ((size_t)kc * BN + j0 + r0 + lane);
        __builtin_amdgcn_global_load_lds(
            (const __attribute__((address_space(1))) void*)g,
            (__attribute__((address_space(3))) void*)(buf + cb),
            16, 0, 0);
    }
}

// Block: 256 thr = 4 waves (2 wm x 2 wn), block tile 128x128, wave tile 64x64
// (mf=nf=4, 16x16x32 MFMA). A-frags resident in regs (64 VGPR), Bs in LDS
// double-buffered (2 x 32KB), staged via global_load_lds. One barrier per jt.
// Grid: (64 i-tiles, 8 j-splits) = 512 blocks = 2/CU.
__global__ __launch_bounds__(256, 2) void main_kernel(const short8* __restrict__ fbT,
                                                      const int* __restrict__ lbl,
                                                      const float* __restrict__ sq,
                                                      float4* __restrict__ part) {
    __shared__ short8 Bs0[2048];  // [kc*128 + r]
    __shared__ short8 Bs1[2048];
    __shared__ float4 mrg[128];

    const int t = threadIdx.x;
    const int lane = t & 63;
    const int wv = t >> 6;       // 0..3
    const int wm = wv >> 1;      // 0..1 : 64-row strip
    const int wn = wv & 1;       // 0..1 : 64-col strip
    const int q = lane >> 4, c = lane & 15;
    const int i0 = blockIdx.x * 128;
    const int jb = blockIdx.y * 1024;

    // stage first tile, then load A-frags/labels while it flies
    stage_tile(fbT, Bs0, jb, wv, lane);

    // A-frags: A[m=c][k=q*8+j]; for ks-th MFMA chunk kc = ks*4+q
    short8 a[4][4];
#pragma unroll
    for (int mf = 0; mf < 4; ++mf) {
        int row = i0 + wm * 64 + mf * 16 + c;
#pragma unroll
        for (int ks = 0; ks < 4; ++ks)
            a[mf][ks] = fbT[(size_t)(ks * 4 + q) * BN + row];
    }
    int li[4][4];
#pragma unroll
    for (int mf = 0; mf < 4; ++mf)
#pragma unroll
        for (int rg = 0; rg < 4; ++rg)
            li[mf][rg] = lbl[i0 + wm * 64 + mf * 16 + q * 4 + rg];

    float s1[4][4], s2[4][4], n1[4][4];
#pragma unroll
    for (int mf = 0; mf < 4; ++mf)
#pragma unroll
        for (int rg = 0; rg < 4; ++rg) {
            s1[mf][rg] = INFINITY; s2[mf][rg] = INFINITY; n1[mf][rg] = INFINITY;
        }

    __syncthreads();  // tile 0 resident (syncthreads drains vmcnt)

#pragma unroll
    for (int jt = 0; jt < 8; ++jt) {
        short8* cur = (jt & 1) ? Bs1 : Bs0;
        short8* nxt = (jt & 1) ? Bs0 : Bs1;
        const int j0 = jb + jt * 128;
        if (jt < 7) stage_tile(fbT, nxt, j0 + 128, wv, lane);

        // per-lane label/sq for the 16 j-columns this lane covers
        int ljv[4]; float sjv[4];
#pragma unroll
        for (int nf = 0; nf < 4; ++nf) {
            int jc = j0 + wn * 64 + nf * 16 + c;
            ljv[nf] = lbl[jc];
            sjv[nf] = sq[jc];
        }

        floatx4 acc[4][4];
#pragma unroll
        for (int mf = 0; mf < 4; ++mf)
#pragma unroll
            for (int nf = 0; nf < 4; ++nf) acc[mf][nf] = (floatx4)0.f;

#pragma unroll
        for (int ks = 0; ks < 4; ++ks) {
            short8 b[4];
#pragma unroll
            for (int nf = 0; nf < 4; ++nf)
                b[nf] = cur[(ks * 4 + q) * 128 + wn * 64 + nf * 16 + c];
#pragma unroll
            for (int mf = 0; mf < 4; ++mf)
#pragma unroll
                for (int nf = 0; nf < 4; ++nf)
                    acc[mf][nf] = __builtin_amdgcn_mfma_f32_16x16x32_bf16(
                        a[mf][ks], b[nf], acc[mf][nf], 0, 0, 0);
        }

        // fold v = sq_j - 2*dot; C/D map col=c, row=q*4+rg
#pragma unroll
        for (int nf = 0; nf < 4; ++nf) {
#pragma unroll
            for (int mf = 0; mf < 4; ++mf)
#pragma unroll
                for (int rg = 0; rg < 4; ++rg) {
                    float v = fmaf(-2.0f, acc[mf][nf][rg], sjv[nf]);
                    bool same = (li[mf][rg] == ljv[nf]);
                    float vs = same ? v : INFINITY;
                    float vd = same ? INFINITY : v;
                    s2[mf][rg] = fminf(s2[mf][rg], fmaxf(s1[mf][rg], vs));
                    s1[mf][rg] = fminf(s1[mf][rg], vs);
                    n1[mf][rg] = fminf(n1[mf][rg], vd);
                }
        }
        __syncthreads();  // all reads of cur done; next tile resident
    }

    // merge across the 16 column-lanes (c) sharing each accumulator row
#pragma unroll
    for (int m = 1; m < 16; m <<= 1) {
#pragma unroll
        for (int mf = 0; mf < 4; ++mf)
#pragma unroll
            for (int rg = 0; rg < 4; ++rg) {
                float o1 = __shfl_xor(s1[mf][rg], m, 16);
                float o2 = __shfl_xor(s2[mf][rg], m, 16);
                float on = __shfl_xor(n1[mf][rg], m, 16);
                float lo = fminf(s1[mf][rg], o1);
                float hi = fminf(fmaxf(s1[mf][rg], o1), fminf(s2[mf][rg], o2));
                s1[mf][rg] = lo; s2[mf][rg] = hi;
                n1[mf][rg] = fminf(n1[mf][rg], on);
            }
    }

    // in-block merge of the wn pair via LDS, one slice write per jpart
    if (c == 0 && wn == 1) {
#pragma unroll
        for (int mf = 0; mf < 4; ++mf)
#pragma unroll
            for (int rg = 0; rg < 4; ++rg) {
                int row = wm * 64 + mf * 16 + q * 4 + rg;
                mrg[row] = make_float4(s1[mf][rg], s2[mf][rg], n1[mf][rg], 0.f);
            }
    }
    __syncthreads();
    if (c == 0 && wn == 0) {
#pragma unroll
        for (int mf = 0; mf < 4; ++mf)
#pragma unroll
            for (int rg = 0; rg < 4; ++rg) {
                int row = wm * 64 + mf * 16 + q * 4 + rg;
                float4 o = mrg[row];
                float a1 = s1[mf][rg], a2 = s2[mf][rg];
                float lo = fminf(a1, o.x);
                float hi = fminf(fmaxf(a1, o.x), fminf(a2, o.y));
                float nn = fminf(n1[mf][rg], o.z);
                part[blockIdx.y * BN + i0 + row] = make_float4(lo, hi, nn, 0.f);
            }
    }
}

// single fused merge: 64 blocks, last block (atomic counter) writes the mean
__global__ __launch_bounds__(128) void merge_kernel(const float4* __restrict__ part,
                                                    const float* __restrict__ sq,
                                                    float* __restrict__ g_acc,
                                                    unsigned* __restrict__ counter,
                                                    float* __restrict__ out) {
    int r = blockIdx.x * 128 + threadIdx.x;
    float s1 = INFINITY, s2v = INFINITY, n = INFINITY;
#pragma unroll
    for (int k = 0; k < 8; ++k) {
        float4 pp = part[k * BN + r];
        float lo = fminf(s1, pp.x);
        float hi = fminf(fmaxf(s1, pp.x), fminf(s2v, pp.y));
        s1 = lo; s2v = hi;
        n = fminf(n, pp.z);
    }
    float si = sq[r];
    float pos = sqrtf(fmaxf(si + s2v + EPS_F, 0.f));
    float neg = sqrtf(fmaxf(si + n + EPS_F, 0.f));
    float h = fmaxf(MARGIN_F + pos - neg, 0.f);
    __shared__ float red[2];
#pragma unroll
    for (int m = 32; m >= 1; m >>= 1) h += __shfl_down(h, m, 64);
    if ((threadIdx.x & 63) == 0) red[threadIdx.x >> 6] = h;
    __syncthreads();
    if (threadIdx.x == 0) {
        atomicAdd(g_acc, red[0] + red[1]);
        __threadfence();
        unsigned old = atomicAdd(counter, 1u);
        if (old == 63u) {
            float tot = atomicAdd(g_acc, 0.0f);  // returns full sum
            out[0] = tot / (float)BN;
        }
    }
}

extern "C" void kernel_launch(void* const* d_in, const int* in_sizes, int n_in,
                              void* d_out, int out_size, void* d_ws, size_t ws_size,
                              hipStream_t stream) {
    const float* f = (const float*)d_in[0];
    const int* lbl = (const int*)d_in[1];
    float* sq = (float*)d_ws;
    short8* fbT = (short8*)((char*)d_ws + 32768);
    float4* part = (float4*)((char*)d_ws + 32768 + 2097152);
    float* g_acc = (float*)((char*)d_ws + 32768 + 2097152 + 1048576);
    unsigned* counter = (unsigned*)(g_acc + 1);
    float* out = (float*)d_out;

    prep_kernel<<<128, 256, 0, stream>>>(f, fbT, sq, g_acc, counter);
    main_kernel<<<dim3(64, 8), 256, 0, stream>>>(fbT, lbl, sq, part);
    merge_kernel<<<64, 128, 0, stream>>>(part, sq, g_acc, counter, out);
}

// Round 5
// 93.390 us; speedup vs baseline: 1.0949x; 1.0949x over previous
//
#include <hip/hip_runtime.h>
#include <math.h>

// TripletHard B=8192 D=128 NC=256. MFMA bf16 Gram + streaming min-tracking.
// v[i][j] = sq_j - 2*dot(i,j) tracked (monotone shift by sq_i applied at end).
// fbT is K-MAJOR chunked: fbT8[kc * 8192 + row] = features[row][kc*8..kc*8+7].
// Main kernel is BARRIER-FREE and LDS-FREE: fbT (2 MB) is L2-resident, so each
// wave loads its B-fragments straight global->VGPR and free-runs (no
// __syncthreads -> no vmcnt(0) drain pathology; r4 post-mortem).
// ws: [0,32K) sq fp32[8192]; [32K,32K+2M) fbT; [32K+2M,+2M) part float4[16][8192];
//     then g_acc float, counter uint.

#define BN 8192
#define MARGIN_F 1.0f
#define EPS_F 1e-5f

typedef __attribute__((ext_vector_type(8))) short short8;
typedef __attribute__((ext_vector_type(4))) float floatx4;

__device__ __forceinline__ unsigned short bf16_rne(float x, float& r) {
    unsigned u = __float_as_uint(x);
    u += 0x7FFF + ((u >> 16) & 1);
    unsigned short h = (unsigned short)(u >> 16);
    r = __uint_as_float(((unsigned)h) << 16);
    return h;
}

// 4 threads per row: convert to bf16 (RNE), write K-major chunks, sq from
// ROUNDED values. Also zero-inits the merge kernel's acc/counter.
__global__ __launch_bounds__(256) void prep_kernel(const float* __restrict__ f,
                                                   short8* __restrict__ fbT,
                                                   float* __restrict__ sq,
                                                   float* __restrict__ g_acc,
                                                   unsigned* __restrict__ counter) {
    int gid = blockIdx.x * 256 + threadIdx.x;  // 0..32767
    if (gid == 0) { *g_acc = 0.f; *counter = 0u; }
    int row = gid >> 2, part = gid & 3;
    const float4* f4 = (const float4*)f + (size_t)row * 32 + part * 8;
    float s = 0.f;
#pragma unroll
    for (int cc = 0; cc < 4; ++cc) {  // chunk kc = part*4 + cc
        float4 v0 = f4[cc * 2], v1 = f4[cc * 2 + 1];
        float r0, r1, r2, r3, r4, r5, r6, r7;
        short8 o;
        o[0] = (short)bf16_rne(v0.x, r0);
        o[1] = (short)bf16_rne(v0.y, r1);
        o[2] = (short)bf16_rne(v0.z, r2);
        o[3] = (short)bf16_rne(v0.w, r3);
        o[4] = (short)bf16_rne(v1.x, r4);
        o[5] = (short)bf16_rne(v1.y, r5);
        o[6] = (short)bf16_rne(v1.z, r6);
        o[7] = (short)bf16_rne(v1.w, r7);
        fbT[(size_t)(part * 4 + cc) * BN + row] = o;
        s += r0 * r0 + r1 * r1 + r2 * r2 + r3 * r3 +
             r4 * r4 + r5 * r5 + r6 * r6 + r7 * r7;
    }
    s += __shfl_xor(s, 1, 4);
    s += __shfl_xor(s, 2, 4);
    if (part == 0) sq[row] = s;
}

// Block: 256 thr = 4 waves, each wave an INDEPENDENT 64-row i-strip
// (i0 = bx*256 + wv*64). Wave tile 64x64 (mf=nf=4), A-frags resident in regs,
// B-frags loaded global->VGPR per tile (L2-resident fbT). No LDS, no barriers.
// Grid: (32 i-blocks, 16 j-splits) = 512 blocks = 2/CU = 2 waves/SIMD.
// Each wave scans 512 j's = 8 tiles of 64.
__global__ __launch_bounds__(256, 2) void main_kernel(const short8* __restrict__ fbT,
                                                      const int* __restrict__ lbl,
                                                      const float* __restrict__ sq,
                                                      float4* __restrict__ part) {
    const int t = threadIdx.x;
    const int lane = t & 63;
    const int wv = t >> 6;       // 0..3 -> own 64-row strip
    const int q = lane >> 4, c = lane & 15;
    const int i0 = blockIdx.x * 256 + wv * 64;
    const int jb = blockIdx.y * 512;

    // A-frags: A[m=c][k=q*8+j]; chunk for ks-th MFMA = ks*4+q
    short8 a[4][4];
#pragma unroll
    for (int mf = 0; mf < 4; ++mf) {
        int row = i0 + mf * 16 + c;
#pragma unroll
        for (int ks = 0; ks < 4; ++ks)
            a[mf][ks] = fbT[(size_t)(ks * 4 + q) * BN + row];
    }
    int li[4][4];
#pragma unroll
    for (int mf = 0; mf < 4; ++mf)
#pragma unroll
        for (int rg = 0; rg < 4; ++rg)
            li[mf][rg] = lbl[i0 + mf * 16 + q * 4 + rg];

    float s1[4][4], s2[4][4], n1[4][4];
#pragma unroll
    for (int mf = 0; mf < 4; ++mf)
#pragma unroll
        for (int rg = 0; rg < 4; ++rg) {
            s1[mf][rg] = INFINITY; s2[mf][rg] = INFINITY; n1[mf][rg] = INFINITY;
        }

#pragma unroll 2
    for (int jt = 0; jt < 8; ++jt) {
        const int j0 = jb + jt * 64;

        // B-frags straight from global (L2): chunk ks*4+q of rows j0+nf*16+c
        short8 b[4][4];
#pragma unroll
        for (int ks = 0; ks < 4; ++ks)
#pragma unroll
            for (int nf = 0; nf < 4; ++nf)
                b[ks][nf] = fbT[(size_t)(ks * 4 + q) * BN + j0 + nf * 16 + c];

        int ljv[4]; float sjv[4];
#pragma unroll
        for (int nf = 0; nf < 4; ++nf) {
            int jc = j0 + nf * 16 + c;
            ljv[nf] = lbl[jc];
            sjv[nf] = sq[jc];
        }

        floatx4 acc[4][4];
#pragma unroll
        for (int mf = 0; mf < 4; ++mf)
#pragma unroll
            for (int nf = 0; nf < 4; ++nf) acc[mf][nf] = (floatx4)0.f;

#pragma unroll
        for (int ks = 0; ks < 4; ++ks)
#pragma unroll
            for (int mf = 0; mf < 4; ++mf)
#pragma unroll
                for (int nf = 0; nf < 4; ++nf)
                    acc[mf][nf] = __builtin_amdgcn_mfma_f32_16x16x32_bf16(
                        a[mf][ks], b[ks][nf], acc[mf][nf], 0, 0, 0);

        // fold v = sq_j - 2*dot; C/D map col=c, row=q*4+rg
#pragma unroll
        for (int nf = 0; nf < 4; ++nf) {
#pragma unroll
            for (int mf = 0; mf < 4; ++mf)
#pragma unroll
                for (int rg = 0; rg < 4; ++rg) {
                    float v = fmaf(-2.0f, acc[mf][nf][rg], sjv[nf]);
                    bool same = (li[mf][rg] == ljv[nf]);
                    float vs = same ? v : INFINITY;
                    float vd = same ? INFINITY : v;
                    s2[mf][rg] = fminf(s2[mf][rg], fmaxf(s1[mf][rg], vs));
                    s1[mf][rg] = fminf(s1[mf][rg], vs);
                    n1[mf][rg] = fminf(n1[mf][rg], vd);
                }
        }
    }

    // merge across the 16 column-lanes (c) sharing each accumulator row
#pragma unroll
    for (int m = 1; m < 16; m <<= 1) {
#pragma unroll
        for (int mf = 0; mf < 4; ++mf)
#pragma unroll
            for (int rg = 0; rg < 4; ++rg) {
                float o1 = __shfl_xor(s1[mf][rg], m, 16);
                float o2 = __shfl_xor(s2[mf][rg], m, 16);
                float on = __shfl_xor(n1[mf][rg], m, 16);
                float lo = fminf(s1[mf][rg], o1);
                float hi = fminf(fmaxf(s1[mf][rg], o1), fminf(s2[mf][rg], o2));
                s1[mf][rg] = lo; s2[mf][rg] = hi;
                n1[mf][rg] = fminf(n1[mf][rg], on);
            }
    }

    // each wave owns distinct rows -> direct slice write, no cross-wave merge
    if (c == 0) {
#pragma unroll
        for (int mf = 0; mf < 4; ++mf)
#pragma unroll
            for (int rg = 0; rg < 4; ++rg) {
                int row = i0 + mf * 16 + q * 4 + rg;
                part[blockIdx.y * BN + row] =
                    make_float4(s1[mf][rg], s2[mf][rg], n1[mf][rg], 0.f);
            }
    }
}

// single fused merge: 64 blocks, last block (atomic counter) writes the mean
__global__ __launch_bounds__(128) void merge_kernel(const float4* __restrict__ part,
                                                    const float* __restrict__ sq,
                                                    float* __restrict__ g_acc,
                                                    unsigned* __restrict__ counter,
                                                    float* __restrict__ out) {
    int r = blockIdx.x * 128 + threadIdx.x;
    float s1 = INFINITY, s2v = INFINITY, n = INFINITY;
#pragma unroll
    for (int k = 0; k < 16; ++k) {
        float4 pp = part[k * BN + r];
        float lo = fminf(s1, pp.x);
        float hi = fminf(fmaxf(s1, pp.x), fminf(s2v, pp.y));
        s1 = lo; s2v = hi;
        n = fminf(n, pp.z);
    }
    float si = sq[r];
    float pos = sqrtf(fmaxf(si + s2v + EPS_F, 0.f));
    float neg = sqrtf(fmaxf(si + n + EPS_F, 0.f));
    float h = fmaxf(MARGIN_F + pos - neg, 0.f);
    __shared__ float red[2];
#pragma unroll
    for (int m = 32; m >= 1; m >>= 1) h += __shfl_down(h, m, 64);
    if ((threadIdx.x & 63) == 0) red[threadIdx.x >> 6] = h;
    __syncthreads();
    if (threadIdx.x == 0) {
        atomicAdd(g_acc, red[0] + red[1]);
        __threadfence();
        unsigned old = atomicAdd(counter, 1u);
        if (old == 63u) {
            float tot = atomicAdd(g_acc, 0.0f);  // returns full sum
            out[0] = tot / (float)BN;
        }
    }
}

extern "C" void kernel_launch(void* const* d_in, const int* in_sizes, int n_in,
                              void* d_out, int out_size, void* d_ws, size_t ws_size,
                              hipStream_t stream) {
    const float* f = (const float*)d_in[0];
    const int* lbl = (const int*)d_in[1];
    float* sq = (float*)d_ws;
    short8* fbT = (short8*)((char*)d_ws + 32768);
    float4* part = (float4*)((char*)d_ws + 32768 + 2097152);
    float* g_acc = (float*)((char*)d_ws + 32768 + 2097152 + 2097152);
    unsigned* counter = (unsigned*)(g_acc + 1);
    float* out = (float*)d_out;

    prep_kernel<<<128, 256, 0, stream>>>(f, fbT, sq, g_acc, counter);
    main_kernel<<<dim3(32, 16), 256, 0, stream>>>(fbT, lbl, sq, part);
    merge_kernel<<<64, 128, 0, stream>>>(part, sq, g_acc, counter, out);
}